// Round 2
// baseline (684.429 us; speedup 1.0000x reference)
//
#include <hip/hip_runtime.h>

// HardAttention: out[b,c] = sum_t max_s ( xs[b,t,:] . ys[b,c,s,:] )
// B=16, Tx=128, C=64, Ty=128, d=768. fp32 in, fp32 out.
// One block per (b,c); 128x128 score tile via bf16 MFMA 16x16x32.
// A = pre-converted bf16 xs in d_ws (L2-resident, 3 MB). B = ys streamed
// fp32 from HBM exactly once (nontemporal), converted inline.
// K-loop register-double-buffered: iter k+1 loads issued before iter k
// compute so HBM latency hides behind MFMA+convert at 2 waves/SIMD.
// Floor: 403 MB @ 6.5 TB/s ~= 62 us for the main kernel.

typedef __attribute__((ext_vector_type(8))) short short8;   // 8 x bf16 (4 VGPR)
typedef __attribute__((ext_vector_type(4))) float floatx4;  // MFMA acc / loads

#define B_DIM 16
#define TX 128
#define CC 64
#define TY 128
#define DD 768
#define KITERS (DD / 32)  // 24

__device__ __forceinline__ short f2bf(float f) {
  // round-to-nearest-even fp32 -> bf16 (inputs finite; no NaN handling)
  unsigned u = __builtin_bit_cast(unsigned, f);
  u += 0x7FFFu + ((u >> 16) & 1u);
  return (short)(u >> 16);
}

__device__ __forceinline__ floatx4 ntload4(const float* p) {
  return __builtin_nontemporal_load(reinterpret_cast<const floatx4*>(p));
}

// ---- pre-pass: convert xs (fp32) -> bf16 into workspace -------------------
__global__ __launch_bounds__(256) void cvt_xs(const float* __restrict__ xs,
                                              short* __restrict__ xb, int n4) {
  int i = blockIdx.x * blockDim.x + threadIdx.x;
  if (i >= n4) return;
  float4 v = reinterpret_cast<const float4*>(xs)[i];
  short4 o;
  o.x = f2bf(v.x);
  o.y = f2bf(v.y);
  o.z = f2bf(v.z);
  o.w = f2bf(v.w);
  reinterpret_cast<short4*>(xb)[i] = o;
}

// ---- main kernel ----------------------------------------------------------
__global__ __launch_bounds__(256, 2) void hardattn(const short* __restrict__ xb,
                                                   const float* __restrict__ ys,
                                                   float* __restrict__ out) {
  const int blk = blockIdx.x;     // = b*64 + c
  const int b = blk >> 6;
  const int tid = threadIdx.x;
  const int w = tid >> 6;         // wave 0..3 -> s-cols [32w, 32w+32)
  const int lane = tid & 63;
  const int l16 = lane & 15;      // A: row m ; B: row s ; D: col s
  const int kg = lane >> 4;       // input: k-group ; D: row-group

  const float* Bp = ys + (size_t)blk * TY * DD;  // ys[b][c] : [128][768]

  floatx4 acc[8][2];
#pragma unroll
  for (int mt = 0; mt < 8; mt++)
#pragma unroll
    for (int nt = 0; nt < 2; nt++) acc[mt][nt] = (floatx4)0.f;

  const short* aBase = xb + (size_t)b * TX * DD + (size_t)l16 * DD + kg * 8;
  const float* bBase0 = Bp + (size_t)(w * 32 + l16) * DD + kg * 8;
  const float* bBase1 = bBase0 + (size_t)16 * DD;

  // register double buffers
  short8 abuf[2][8];
  floatx4 bbuf[2][4];

  // prime iteration 0 (B first: longest latency)
  bbuf[0][0] = ntload4(bBase0);
  bbuf[0][1] = ntload4(bBase0 + 4);
  bbuf[0][2] = ntload4(bBase1);
  bbuf[0][3] = ntload4(bBase1 + 4);
#pragma unroll
  for (int mt = 0; mt < 8; mt++)
    abuf[0][mt] = *reinterpret_cast<const short8*>(aBase + (size_t)mt * 16 * DD);

#pragma unroll
  for (int it = 0; it < KITERS; it++) {
    const int cur = it & 1;
    const int nxt = cur ^ 1;
    if (it + 1 < KITERS) {
      const int kn = (it + 1) * 32;
      bbuf[nxt][0] = ntload4(bBase0 + kn);
      bbuf[nxt][1] = ntload4(bBase0 + kn + 4);
      bbuf[nxt][2] = ntload4(bBase1 + kn);
      bbuf[nxt][3] = ntload4(bBase1 + kn + 4);
#pragma unroll
      for (int mt = 0; mt < 8; mt++)
        abuf[nxt][mt] =
            *reinterpret_cast<const short8*>(aBase + (size_t)mt * 16 * DD + kn);
    }

    // convert current B to bf16
    short8 bf0, bf1;
#pragma unroll
    for (int j = 0; j < 4; j++) {
      bf0[j] = f2bf(bbuf[cur][0][j]);
      bf0[j + 4] = f2bf(bbuf[cur][1][j]);
      bf1[j] = f2bf(bbuf[cur][2][j]);
      bf1[j + 4] = f2bf(bbuf[cur][3][j]);
    }

    // MFMA: D[row = m][col = s]
#pragma unroll
    for (int mt = 0; mt < 8; mt++) {
      acc[mt][0] =
          __builtin_amdgcn_mfma_f32_16x16x32_bf16(abuf[cur][mt], bf0, acc[mt][0], 0, 0, 0);
      acc[mt][1] =
          __builtin_amdgcn_mfma_f32_16x16x32_bf16(abuf[cur][mt], bf1, acc[mt][1], 0, 0, 0);
    }
  }

  // ---- epilogue: max over s (cols), then sum over t (rows) ----
  // C/D layout (verified m89/m91): col = lane&15, row = (lane>>4)*4 + reg
  __shared__ float part[4][TX];  // per-wave per-row max over its 32 cols
  __shared__ float wsum[2];

#pragma unroll
  for (int mt = 0; mt < 8; mt++) {
#pragma unroll
    for (int r = 0; r < 4; r++) {
      float v = fmaxf(acc[mt][0][r], acc[mt][1][r]);
      v = fmaxf(v, __shfl_xor(v, 1, 64));
      v = fmaxf(v, __shfl_xor(v, 2, 64));
      v = fmaxf(v, __shfl_xor(v, 4, 64));
      v = fmaxf(v, __shfl_xor(v, 8, 64));
      if (l16 == 0) part[w][mt * 16 + kg * 4 + r] = v;
    }
  }
  __syncthreads();

  if (tid < 128) {
    float rm = fmaxf(fmaxf(part[0][tid], part[1][tid]),
                     fmaxf(part[2][tid], part[3][tid]));
    float s = rm;
    s += __shfl_down(s, 32, 64);
    s += __shfl_down(s, 16, 64);
    s += __shfl_down(s, 8, 64);
    s += __shfl_down(s, 4, 64);
    s += __shfl_down(s, 2, 64);
    s += __shfl_down(s, 1, 64);
    if (lane == 0) wsum[w] = s;
  }
  __syncthreads();
  if (tid == 0) out[blk] = wsum[0] + wsum[1];
}

extern "C" void kernel_launch(void* const* d_in, const int* in_sizes, int n_in,
                              void* d_out, int out_size, void* d_ws, size_t ws_size,
                              hipStream_t stream) {
  const float* xs = (const float*)d_in[0];  // (16,128,768)
  const float* ys = (const float*)d_in[1];  // (16,64,128,768)
  float* out = (float*)d_out;               // (16,64)

  const size_t xs_elems = (size_t)B_DIM * TX * DD;  // 1,572,864
  short* xb = (short*)d_ws;                         // 3 MB of workspace
  int n4 = (int)(xs_elems / 4);
  cvt_xs<<<(n4 + 255) / 256, 256, 0, stream>>>(xs, xb, n4);
  hardattn<<<B_DIM * CC, 256, 0, stream>>>(xb, ys, out);
}

// Round 3
// 559.405 us; speedup vs baseline: 1.2235x; 1.2235x over previous
//
#include <hip/hip_runtime.h>
#include <stdint.h>

// HardAttention: out[b,c] = sum_t max_s ( xs[b,t,:] . ys[b,c,s,:] )
// B=16, Tx=128, C=64, Ty=128, d=768. fp32 in, fp32 out.
// One block per (b,c); 128x128 score tile via bf16 MFMA 16x16x32.
//   A = pre-converted bf16 xs in d_ws (L2/L3-resident, 3 MB), direct loads.
//   B = ys staged fp32 HBM -> LDS via global_load_lds dwordx4 (coalesced,
//       16 KB/iter/block, double-buffered), converted to bf16 at ds_read.
// Each wave stages exactly the 32 s-rows it consumes. XOR swizzle of 16B
// k-chunks within each 128B LDS row kills ds_read_b128 bank conflicts
// (2-way residual = free) without breaking global_load_lds contiguity.
// 16KB in flight per block per barrier period => latency-robust; BW-bound
// floor ~65us for the main kernel (403 MB @ 6.3 TB/s).

typedef __attribute__((ext_vector_type(8))) short short8;   // 8 x bf16
typedef __attribute__((ext_vector_type(4))) float floatx4;  // MFMA acc / 16B

#define B_DIM 16
#define TX 128
#define CC 64
#define TY 128
#define DD 768
#define BK 32
#define KITERS (DD / BK)  // 24

__device__ __forceinline__ short f2bf(float f) {
  // round-to-nearest-even fp32 -> bf16 (inputs finite; no NaN handling)
  unsigned u = __builtin_bit_cast(unsigned, f);
  u += 0x7FFFu + ((u >> 16) & 1u);
  return (short)(u >> 16);
}

// ---- pre-pass: convert xs (fp32) -> bf16 into workspace -------------------
__global__ __launch_bounds__(256) void cvt_xs(const float* __restrict__ xs,
                                              short* __restrict__ xb, int n4) {
  int i = blockIdx.x * blockDim.x + threadIdx.x;
  if (i >= n4) return;
  float4 v = reinterpret_cast<const float4*>(xs)[i];
  short4 o;
  o.x = f2bf(v.x);
  o.y = f2bf(v.y);
  o.z = f2bf(v.z);
  o.w = f2bf(v.w);
  reinterpret_cast<short4*>(xb)[i] = o;
}

// ---- main kernel ----------------------------------------------------------
__global__ __launch_bounds__(256, 3) void hardattn(const short* __restrict__ xb,
                                                   const float* __restrict__ ys,
                                                   float* __restrict__ out) {
  __shared__ float bstage[2][TY * BK];  // 2 x 16 KB fp32 staging for ys tile
  __shared__ float part[4][TX];         // epilogue per-wave row maxes
  __shared__ float wsum[2];

  const int blk = blockIdx.x;  // = b*64 + c
  const int b = blk >> 6;
  const int tid = threadIdx.x;
  const int w = tid >> 6;      // wave 0..3 -> s-rows [32w, 32w+32)
  const int lane = tid & 63;
  const int l16 = lane & 15;   // A row m ; B row s ; D col s
  const int kg = lane >> 4;    // input k-group ; D row-group

  const float* Bp = ys + (size_t)blk * TY * DD;  // ys[b][c] : [128][768]

  // ---- staging geometry (wave w stages rows w*32 .. w*32+31) ----
  // Per instr j: 64 lanes x 16B = 8 rows x 128B. lane -> row w*32+8j+(lane>>3),
  // 16B chunk (lane&7). LDS holds [s][32 floats], row-contiguous, with the
  // k-chunk position XOR-swizzled by (row & 7) (j-invariant since 8j%8==0).
  const int srow = (w << 5) + (lane >> 3);
  const int gchunk = (lane & 7) ^ (srow & 7);
  const float* gsrc = Bp + (size_t)srow * DD + gchunk * 4;

#define STAGE(bufidx, k0)                                                  \
  {                                                                        \
    _Pragma("unroll") for (int j = 0; j < 4; j++) {                        \
      const float* g = gsrc + (size_t)(8 * j) * DD + (k0);                 \
      float* l = &bstage[bufidx][((w << 5) + 8 * j) * BK];                 \
      __builtin_amdgcn_global_load_lds(                                    \
          (const __attribute__((address_space(1))) void*)g,                \
          (__attribute__((address_space(3))) void*)l, 16, 0, 0);           \
    }                                                                      \
  }

  floatx4 acc[8][2];
#pragma unroll
  for (int mt = 0; mt < 8; mt++)
#pragma unroll
    for (int nt = 0; nt < 2; nt++) acc[mt][nt] = (floatx4)0.f;

  const short* aBase = xb + (size_t)b * TX * DD + (size_t)l16 * DD + kg * 8;

  // fragment read offsets (lane-constant): s&7 == l16&7 for both n-tiles
  const int p0 = ((kg << 1) ^ (l16 & 7)) * 4;        // floats
  const int p1 = (((kg << 1) | 1) ^ (l16 & 7)) * 4;  // floats
  const int rb0 = ((w << 5) + l16) * BK;             // n-tile 0 row base
  const int rb1 = ((w << 5) + 16 + l16) * BK;        // n-tile 1 row base

  STAGE(0, 0);  // prologue

  for (int it = 0; it < KITERS; it++) {
    __syncthreads();  // drains vmcnt -> buf[cur] staged
    const int cur = it & 1;
    if (it + 1 < KITERS) STAGE(cur ^ 1, (it + 1) * BK);  // async prefetch
    const int k0 = it * BK;

    // A fragments: 8 x 16B per lane, bf16, from L2/L3-resident xb
    short8 a[8];
#pragma unroll
    for (int mt = 0; mt < 8; mt++)
      a[mt] = *reinterpret_cast<const short8*>(aBase + (size_t)mt * 16 * DD + k0);

    // B fragments from LDS (4 x ds_read_b128, swizzled) + convert
    const float* rb = &bstage[cur][0];
    floatx4 c00 = *reinterpret_cast<const floatx4*>(rb + rb0 + p0);
    floatx4 c01 = *reinterpret_cast<const floatx4*>(rb + rb0 + p1);
    floatx4 c10 = *reinterpret_cast<const floatx4*>(rb + rb1 + p0);
    floatx4 c11 = *reinterpret_cast<const floatx4*>(rb + rb1 + p1);
    short8 bf0, bf1;
#pragma unroll
    for (int j = 0; j < 4; j++) {
      bf0[j] = f2bf(c00[j]);
      bf0[j + 4] = f2bf(c01[j]);
      bf1[j] = f2bf(c10[j]);
      bf1[j + 4] = f2bf(c11[j]);
    }

    // MFMA: D[row = m][col = s]
#pragma unroll
    for (int mt = 0; mt < 8; mt++) {
      acc[mt][0] =
          __builtin_amdgcn_mfma_f32_16x16x32_bf16(a[mt], bf0, acc[mt][0], 0, 0, 0);
      acc[mt][1] =
          __builtin_amdgcn_mfma_f32_16x16x32_bf16(a[mt], bf1, acc[mt][1], 0, 0, 0);
    }
  }

  // ---- epilogue: max over s (cols), then sum over t (rows) ----
  // C/D layout (verified m89/m91): col = lane&15, row = (lane>>4)*4 + reg
#pragma unroll
  for (int mt = 0; mt < 8; mt++) {
#pragma unroll
    for (int r = 0; r < 4; r++) {
      float v = fmaxf(acc[mt][0][r], acc[mt][1][r]);
      v = fmaxf(v, __shfl_xor(v, 1, 64));
      v = fmaxf(v, __shfl_xor(v, 2, 64));
      v = fmaxf(v, __shfl_xor(v, 4, 64));
      v = fmaxf(v, __shfl_xor(v, 8, 64));
      if (l16 == 0) part[w][mt * 16 + kg * 4 + r] = v;
    }
  }
  __syncthreads();

  if (tid < 128) {
    float rm = fmaxf(fmaxf(part[0][tid], part[1][tid]),
                     fmaxf(part[2][tid], part[3][tid]));
    float s = rm;
    s += __shfl_down(s, 32, 64);
    s += __shfl_down(s, 16, 64);
    s += __shfl_down(s, 8, 64);
    s += __shfl_down(s, 4, 64);
    s += __shfl_down(s, 2, 64);
    s += __shfl_down(s, 1, 64);
    if (lane == 0) wsum[w] = s;
  }
  __syncthreads();
  if (tid == 0) out[blk] = wsum[0] + wsum[1];
}

extern "C" void kernel_launch(void* const* d_in, const int* in_sizes, int n_in,
                              void* d_out, int out_size, void* d_ws, size_t ws_size,
                              hipStream_t stream) {
  const float* xs = (const float*)d_in[0];  // (16,128,768)
  const float* ys = (const float*)d_in[1];  // (16,64,128,768)
  float* out = (float*)d_out;               // (16,64)

  const size_t xs_elems = (size_t)B_DIM * TX * DD;  // 1,572,864
  short* xb = (short*)d_ws;                         // 3 MB of workspace
  int n4 = (int)(xs_elems / 4);
  cvt_xs<<<(n4 + 255) / 256, 256, 0, stream>>>(xs, xb, n4);
  hardattn<<<B_DIM * CC, 256, 0, stream>>>(xb, ys, out);
}